// Round 1
// baseline (475.479 us; speedup 1.0000x reference)
//
#include <hip/hip_runtime.h>
#include <hip/hip_bf16.h>

// Problem constants
#define BT 2048   // batch
#define DD 512    // input dim
#define HH 512    // hidden dim
#define EE 32     // experts
#define KK 4      // top-k
#define CHN 32    // confidence hidden

// ---------------------------------------------------------------------------
// Gating hidden: h = relu(x @ Wg1 + bg1).  Grid (B/16, 2), 256 thr.
// Block computes 16 rows x 256 cols. Thread: 4 rows x 4 cols.
// ---------------------------------------------------------------------------
__global__ __launch_bounds__(256)
void k_gate_hidden(const float* __restrict__ x, const float* __restrict__ Wg1,
                   const float* __restrict__ bg1, float* __restrict__ h) {
  __shared__ float xs[16][DD];
  const int tid = threadIdx.x;
  const int row0 = blockIdx.x * 16;
  const int cb = blockIdx.y * 256;
  for (int idx = tid; idx < 16 * (DD / 4); idx += 256) {
    int m = idx >> 7, j = idx & 127;
    *reinterpret_cast<float4*>(&xs[m][4 * j]) =
        *reinterpret_cast<const float4*>(&x[(size_t)(row0 + m) * DD + 4 * j]);
  }
  __syncthreads();
  const int cg = tid & 63, rg = tid >> 6;
  const int n0 = cb + cg * 4;
  float acc[4][4];
#pragma unroll
  for (int m = 0; m < 4; m++)
    acc[m][0] = acc[m][1] = acc[m][2] = acc[m][3] = 0.f;
  for (int k = 0; k < DD; k++) {
    float4 w = *reinterpret_cast<const float4*>(&Wg1[(size_t)k * HH + n0]);
#pragma unroll
    for (int m = 0; m < 4; m++) {
      float xv = xs[rg * 4 + m][k];
      acc[m][0] = fmaf(xv, w.x, acc[m][0]);
      acc[m][1] = fmaf(xv, w.y, acc[m][1]);
      acc[m][2] = fmaf(xv, w.z, acc[m][2]);
      acc[m][3] = fmaf(xv, w.w, acc[m][3]);
    }
  }
  float4 bb = *reinterpret_cast<const float4*>(&bg1[n0]);
#pragma unroll
  for (int m = 0; m < 4; m++) {
    int row = row0 + rg * 4 + m;
    float4 o;
    o.x = fmaxf(acc[m][0] + bb.x, 0.f);
    o.y = fmaxf(acc[m][1] + bb.y, 0.f);
    o.z = fmaxf(acc[m][2] + bb.z, 0.f);
    o.w = fmaxf(acc[m][3] + bb.w, 0.f);
    *reinterpret_cast<float4*>(&h[(size_t)row * HH + n0]) = o;
  }
}

// ---------------------------------------------------------------------------
// Gating logits + softmax + top-4 + routing lists. One wave per token.
// Grid (B/4), 256 thr (4 waves).
// ---------------------------------------------------------------------------
__global__ __launch_bounds__(256)
void k_gate_route(const float* __restrict__ h, const float* __restrict__ Wg2,
                  const float* __restrict__ bg2, float* __restrict__ wts,
                  int* __restrict__ cnt, int* __restrict__ tlist) {
  __shared__ float hb[4][HH];
  const int tid = threadIdx.x;
  const int wv = tid >> 6;
  const int lane = tid & 63;
  const int t = blockIdx.x * 4 + wv;
  for (int i = lane; i < HH / 4; i += 64) {
    *reinterpret_cast<float4*>(&hb[wv][4 * i]) =
        *reinterpret_cast<const float4*>(&h[(size_t)t * HH + 4 * i]);
  }
  const int e = lane & 31, half = lane >> 5;
  float acc = 0.f;
  for (int i = 0; i < 256; i++) {
    int k = half * 256 + i;
    acc = fmaf(hb[wv][k], Wg2[(size_t)k * EE + e], acc);
  }
  acc += __shfl_down(acc, 32);
  float logit = acc + bg2[e];
  // softmax over the 32-lane group
  float mx = logit;
#pragma unroll
  for (int m = 16; m >= 1; m >>= 1) mx = fmaxf(mx, __shfl_xor(mx, m, 32));
  float ex = expf(logit - mx);
  float sm = ex;
#pragma unroll
  for (int m = 16; m >= 1; m >>= 1) sm += __shfl_xor(sm, m, 32);
  float w = ex / sm;
  if (half == 0) wts[(size_t)t * EE + e] = w;
  float wcur = w;
  for (int j = 0; j < KK; j++) {
    float v = wcur;
    int vi = e;
#pragma unroll
    for (int m = 16; m >= 1; m >>= 1) {
      float ov = __shfl_xor(v, m, 32);
      int oi = __shfl_xor(vi, m, 32);
      if (ov > v || (ov == v && oi < vi)) { v = ov; vi = oi; }
    }
    if (lane == 0) {
      int pos = atomicAdd(&cnt[vi], 1);
      tlist[(size_t)vi * BT + pos] = (t << 2) | j;
    }
    if (half == 0 && e == vi) wcur = -1.f;
  }
}

// ---------------------------------------------------------------------------
// Expert MLP + confidence for routed pairs. Grid (B/16, E), 256 thr.
// Per block: 16 gathered tokens through expert e's full MLP.
// ---------------------------------------------------------------------------
__global__ __launch_bounds__(256)
void k_expert(const float* __restrict__ x,
              const float* __restrict__ W1, const float* __restrict__ b1,
              const float* __restrict__ W2, const float* __restrict__ b2,
              const float* __restrict__ Wc1, const float* __restrict__ bc1,
              const float* __restrict__ Wc2, const float* __restrict__ bc2,
              const float* __restrict__ wts, const int* __restrict__ cnt,
              const int* __restrict__ tlist,
              float* __restrict__ o_p, float* __restrict__ cw) {
  __shared__ float xs[16][DD];   // x tile, later reused as o tile
  __shared__ float hid[16][HH];
  __shared__ float chb[16][CHN];
  __shared__ int tk[16], sl[16];
  const int e = blockIdx.y;
  const int nt = cnt[e];
  const int start = blockIdx.x * 16;
  if (start >= nt) return;
  const int rows = min(16, nt - start);
  const int tid = threadIdx.x;
  if (tid < 16) {
    int i = min(tid, rows - 1);
    int ent = tlist[(size_t)e * BT + start + i];
    tk[tid] = ent >> 2;
    sl[tid] = ent & 3;
  }
  __syncthreads();
  for (int idx = tid; idx < 16 * (DD / 4); idx += 256) {
    int m = idx >> 7, j = idx & 127;
    *reinterpret_cast<float4*>(&xs[m][4 * j]) =
        *reinterpret_cast<const float4*>(&x[(size_t)tk[m] * DD + 4 * j]);
  }
  __syncthreads();

  const int cg = tid & 127, rg = tid >> 7;
  const int n0 = cg * 4;
  float acc[8][4];

  // GEMM1: hid = relu(xs @ W1[e] + b1[e])
  const float* W1e = W1 + (size_t)e * DD * HH;
#pragma unroll
  for (int m = 0; m < 8; m++)
    acc[m][0] = acc[m][1] = acc[m][2] = acc[m][3] = 0.f;
  for (int k = 0; k < DD; k++) {
    float4 w = *reinterpret_cast<const float4*>(&W1e[(size_t)k * HH + n0]);
#pragma unroll
    for (int m = 0; m < 8; m++) {
      float xv = xs[rg * 8 + m][k];
      acc[m][0] = fmaf(xv, w.x, acc[m][0]);
      acc[m][1] = fmaf(xv, w.y, acc[m][1]);
      acc[m][2] = fmaf(xv, w.z, acc[m][2]);
      acc[m][3] = fmaf(xv, w.w, acc[m][3]);
    }
  }
  {
    float4 bb = *reinterpret_cast<const float4*>(&b1[(size_t)e * HH + n0]);
#pragma unroll
    for (int m = 0; m < 8; m++) {
      int row = rg * 8 + m;
      float4 o;
      o.x = fmaxf(acc[m][0] + bb.x, 0.f);
      o.y = fmaxf(acc[m][1] + bb.y, 0.f);
      o.z = fmaxf(acc[m][2] + bb.z, 0.f);
      o.w = fmaxf(acc[m][3] + bb.w, 0.f);
      *reinterpret_cast<float4*>(&hid[row][n0]) = o;
    }
  }
  __syncthreads();

  // GEMM2: o = hid @ W2[e] + b2[e]   (no relu)
  const float* W2e = W2 + (size_t)e * HH * DD;
#pragma unroll
  for (int m = 0; m < 8; m++)
    acc[m][0] = acc[m][1] = acc[m][2] = acc[m][3] = 0.f;
  for (int k = 0; k < HH; k++) {
    float4 w = *reinterpret_cast<const float4*>(&W2e[(size_t)k * DD + n0]);
#pragma unroll
    for (int m = 0; m < 8; m++) {
      float xv = hid[rg * 8 + m][k];
      acc[m][0] = fmaf(xv, w.x, acc[m][0]);
      acc[m][1] = fmaf(xv, w.y, acc[m][1]);
      acc[m][2] = fmaf(xv, w.z, acc[m][2]);
      acc[m][3] = fmaf(xv, w.w, acc[m][3]);
    }
  }
  {
    float4 bb = *reinterpret_cast<const float4*>(&b2[(size_t)e * DD + n0]);
#pragma unroll
    for (int m = 0; m < 8; m++) {
      int row = rg * 8 + m;
      float4 o;
      o.x = acc[m][0] + bb.x;
      o.y = acc[m][1] + bb.y;
      o.z = acc[m][2] + bb.z;
      o.w = acc[m][3] + bb.w;
      *reinterpret_cast<float4*>(&xs[row][n0]) = o;  // reuse xs as o buffer
      if (row < rows) {
        int t = tk[row], s = sl[row];
        *reinterpret_cast<float4*>(&o_p[((size_t)t * KK + s) * DD + n0]) = o;
      }
    }
  }
  __syncthreads();

  // Confidence layer 1: chb = relu(o @ Wc1[e] + bc1[e])
  const float* Wc1e = Wc1 + (size_t)e * DD * CHN;
#pragma unroll
  for (int r = 0; r < 2; r++) {
    int idx = tid + r * 256;
    int m = idx >> 5, c = idx & 31;
    float a = bc1[(size_t)e * CHN + c];
    for (int k = 0; k < DD; k++) a = fmaf(xs[m][k], Wc1e[(size_t)k * CHN + c], a);
    chb[m][c] = fmaxf(a, 0.f);
  }
  __syncthreads();

  // Confidence layer 2 + cw write
  if (tid < 16) {
    int m = tid;
    float a = bc2[e];
#pragma unroll
    for (int c = 0; c < CHN; c++) a = fmaf(chb[m][c], Wc2[(size_t)e * CHN + c], a);
    float cv = 1.f / (1.f + expf(-a));
    if (m < rows) {
      int t = tk[m];
      cw[(size_t)t * KK + sl[m]] = wts[(size_t)t * EE + e] * cv;
    }
  }
}

// ---------------------------------------------------------------------------
// Combine: out[t] = sum_s cw[t][s]*o[t][s] / (sum_s cw[t][s] + eps)
// ---------------------------------------------------------------------------
__global__ __launch_bounds__(256)
void k_combine(const float* __restrict__ o_p, const float* __restrict__ cw,
               float* __restrict__ out) {
  int gid = blockIdx.x * 256 + threadIdx.x;  // over B * (D/4)
  int t = gid >> 7;
  int j = gid & 127;
  float c0 = cw[t * 4 + 0], c1 = cw[t * 4 + 1];
  float c2 = cw[t * 4 + 2], c3 = cw[t * 4 + 3];
  float den = c0 + c1 + c2 + c3 + 1e-6f;
  const float4* base = reinterpret_cast<const float4*>(o_p) + (size_t)t * 4 * 128;
  float4 v0 = base[0 * 128 + j];
  float4 v1 = base[1 * 128 + j];
  float4 v2 = base[2 * 128 + j];
  float4 v3 = base[3 * 128 + j];
  float4 r;
  r.x = (c0 * v0.x + c1 * v1.x + c2 * v2.x + c3 * v3.x) / den;
  r.y = (c0 * v0.y + c1 * v1.y + c2 * v2.y + c3 * v3.y) / den;
  r.z = (c0 * v0.z + c1 * v1.z + c2 * v2.z + c3 * v3.z) / den;
  r.w = (c0 * v0.w + c1 * v1.w + c2 * v2.w + c3 * v3.w) / den;
  reinterpret_cast<float4*>(out)[gid] = r;
}

extern "C" void kernel_launch(void* const* d_in, const int* in_sizes, int n_in,
                              void* d_out, int out_size, void* d_ws, size_t ws_size,
                              hipStream_t stream) {
  const float* x   = (const float*)d_in[0];
  const float* W1  = (const float*)d_in[1];
  const float* b1  = (const float*)d_in[2];
  const float* W2  = (const float*)d_in[3];
  const float* b2  = (const float*)d_in[4];
  const float* Wg1 = (const float*)d_in[5];
  const float* bg1 = (const float*)d_in[6];
  const float* Wg2 = (const float*)d_in[7];
  const float* bg2 = (const float*)d_in[8];
  const float* Wc1 = (const float*)d_in[9];
  const float* bc1 = (const float*)d_in[10];
  const float* Wc2 = (const float*)d_in[11];
  const float* bc2 = (const float*)d_in[12];
  float* out = (float*)d_out;

  // workspace layout (~21.5 MB)
  float* h_g = (float*)d_ws;                       // B*H
  float* wts = h_g + (size_t)BT * HH;              // B*E
  float* cw  = wts + (size_t)BT * EE;              // B*K
  float* o_p = cw + (size_t)BT * KK;               // B*K*D
  int* cnt   = (int*)(o_p + (size_t)BT * KK * DD); // E
  int* tlist = cnt + EE;                           // E*B

  hipMemsetAsync(cnt, 0, EE * sizeof(int), stream);
  k_gate_hidden<<<dim3(BT / 16, 2), 256, 0, stream>>>(x, Wg1, bg1, h_g);
  k_gate_route<<<BT / 4, 256, 0, stream>>>(h_g, Wg2, bg2, wts, cnt, tlist);
  k_expert<<<dim3(BT / 16, EE), 256, 0, stream>>>(x, W1, b1, W2, b2, Wc1, bc1,
                                                  Wc2, bc2, wts, cnt, tlist,
                                                  o_p, cw);
  k_combine<<<(BT * (DD / 4)) / 256, 256, 0, stream>>>(o_p, cw, out);
}

// Round 2
// 305.890 us; speedup vs baseline: 1.5544x; 1.5544x over previous
//
#include <hip/hip_runtime.h>
#include <hip/hip_bf16.h>

// Problem constants
#define BT 2048   // batch
#define DD 512    // input dim
#define HH 512    // hidden dim
#define EE 32     // experts
#define KK 4      // top-k
#define CHN 32    // confidence hidden
#define ROWS 32   // tokens per expert block

typedef unsigned int u32;
typedef unsigned short u16;
typedef __attribute__((ext_vector_type(8))) short short8;
typedef __attribute__((ext_vector_type(4))) float f32x4;
typedef __attribute__((ext_vector_type(2))) u32 u32x2;
typedef __attribute__((ext_vector_type(4))) u32 u32x4;

__device__ inline u16 f2bf(float f) {  // RNE float->bf16
  u32 u = __builtin_bit_cast(u32, f);
  u32 r = (u + 0x7FFFu + ((u >> 16) & 1u)) >> 16;
  return (u16)r;
}
__device__ inline u32 pack2bf(float a, float b) {
  return (u32)f2bf(a) | ((u32)f2bf(b) << 16);
}
__device__ inline void gload_lds16(const u32* g, u32* l) {
  __builtin_amdgcn_global_load_lds((const __attribute__((address_space(1))) u32*)g,
                                   (__attribute__((address_space(3))) u32*)l, 16, 0, 0);
}

// ---------------------------------------------------------------------------
// x fp32 -> bf16. grid 512, 256 thr, 8 elems/thread.
// ---------------------------------------------------------------------------
__global__ __launch_bounds__(256)
void k_cvt_x(const float* __restrict__ x, u16* __restrict__ xb) {
  int gid = blockIdx.x * 256 + threadIdx.x;
  const float4* src = reinterpret_cast<const float4*>(x) + (size_t)gid * 2;
  float4 a = src[0], b = src[1];
  u32x4 o = { pack2bf(a.x, a.y), pack2bf(a.z, a.w),
              pack2bf(b.x, b.y), pack2bf(b.z, b.w) };
  reinterpret_cast<u32x4*>(xb)[gid] = o;
}

// ---------------------------------------------------------------------------
// W1/W2 -> per-K-step k-contiguous swizzled bf16 fraglet images.
// Image (z, s): 32 KB; fraglet (n, g) at byte n*64 + (g ^ ((n>>2)&3))*16
// holding bf16 W[z][s*32 + g*8 + j][n], j=0..7.
// grid (2 n-chunks, 16 steps, 64 = mat*32+e), 256 thr.
// ---------------------------------------------------------------------------
__global__ __launch_bounds__(256)
void k_tr_w(const float* __restrict__ W1, const float* __restrict__ W2,
            u32* __restrict__ img) {
  int n = blockIdx.x * 256 + threadIdx.x;   // 0..511
  int s = blockIdx.y;                        // 0..15
  int z = blockIdx.z;                        // 0..63
  const float* W = (z < EE) ? (W1 + (size_t)z * DD * HH)
                            : (W2 + (size_t)(z - EE) * HH * DD);
  float v[32];
#pragma unroll
  for (int k = 0; k < 32; k++)
    v[k] = W[(size_t)(s * 32 + k) * 512 + n];
  u32* ob = img + ((size_t)z * 16 + s) * 8192 + n * 16;
  int sw = (n >> 2) & 3;
#pragma unroll
  for (int g = 0; g < 4; g++) {
    u32x4 fr = { pack2bf(v[g * 8 + 0], v[g * 8 + 1]),
                 pack2bf(v[g * 8 + 2], v[g * 8 + 3]),
                 pack2bf(v[g * 8 + 4], v[g * 8 + 5]),
                 pack2bf(v[g * 8 + 6], v[g * 8 + 7]) };
    *reinterpret_cast<u32x4*>(ob + (g ^ sw) * 4) = fr;
  }
}

// ---------------------------------------------------------------------------
// Gating hidden: h = relu(x @ Wg1 + bg1). fp32 (top-k precision).
// ---------------------------------------------------------------------------
__global__ __launch_bounds__(256)
void k_gate_hidden(const float* __restrict__ x, const float* __restrict__ Wg1,
                   const float* __restrict__ bg1, float* __restrict__ h) {
  __shared__ float xs[16][DD];
  const int tid = threadIdx.x;
  const int row0 = blockIdx.x * 16;
  const int cb = blockIdx.y * 256;
  for (int idx = tid; idx < 16 * (DD / 4); idx += 256) {
    int m = idx >> 7, j = idx & 127;
    *reinterpret_cast<float4*>(&xs[m][4 * j]) =
        *reinterpret_cast<const float4*>(&x[(size_t)(row0 + m) * DD + 4 * j]);
  }
  __syncthreads();
  const int cg = tid & 63, rg = tid >> 6;
  const int n0 = cb + cg * 4;
  float acc[4][4];
#pragma unroll
  for (int m = 0; m < 4; m++)
    acc[m][0] = acc[m][1] = acc[m][2] = acc[m][3] = 0.f;
  for (int k = 0; k < DD; k++) {
    float4 w = *reinterpret_cast<const float4*>(&Wg1[(size_t)k * HH + n0]);
#pragma unroll
    for (int m = 0; m < 4; m++) {
      float xv = xs[rg * 4 + m][k];
      acc[m][0] = fmaf(xv, w.x, acc[m][0]);
      acc[m][1] = fmaf(xv, w.y, acc[m][1]);
      acc[m][2] = fmaf(xv, w.z, acc[m][2]);
      acc[m][3] = fmaf(xv, w.w, acc[m][3]);
    }
  }
  float4 bb = *reinterpret_cast<const float4*>(&bg1[n0]);
#pragma unroll
  for (int m = 0; m < 4; m++) {
    int row = row0 + rg * 4 + m;
    float4 o;
    o.x = fmaxf(acc[m][0] + bb.x, 0.f);
    o.y = fmaxf(acc[m][1] + bb.y, 0.f);
    o.z = fmaxf(acc[m][2] + bb.z, 0.f);
    o.w = fmaxf(acc[m][3] + bb.w, 0.f);
    *reinterpret_cast<float4*>(&h[(size_t)row * HH + n0]) = o;
  }
}

// ---------------------------------------------------------------------------
// Gating logits + softmax + top-4 + routing lists. One wave per token.
// ---------------------------------------------------------------------------
__global__ __launch_bounds__(256)
void k_gate_route(const float* __restrict__ h, const float* __restrict__ Wg2,
                  const float* __restrict__ bg2, float* __restrict__ wts,
                  int* __restrict__ cnt, int* __restrict__ tlist) {
  __shared__ float hb[4][HH];
  const int tid = threadIdx.x;
  const int wv = tid >> 6;
  const int lane = tid & 63;
  const int t = blockIdx.x * 4 + wv;
  for (int i = lane; i < HH / 4; i += 64) {
    *reinterpret_cast<float4*>(&hb[wv][4 * i]) =
        *reinterpret_cast<const float4*>(&h[(size_t)t * HH + 4 * i]);
  }
  const int e = lane & 31, half = lane >> 5;
  float acc = 0.f;
  for (int i = 0; i < 256; i++) {
    int k = half * 256 + i;
    acc = fmaf(hb[wv][k], Wg2[(size_t)k * EE + e], acc);
  }
  acc += __shfl_down(acc, 32);
  float logit = acc + bg2[e];
  float mx = logit;
#pragma unroll
  for (int m = 16; m >= 1; m >>= 1) mx = fmaxf(mx, __shfl_xor(mx, m, 32));
  float ex = expf(logit - mx);
  float sm = ex;
#pragma unroll
  for (int m = 16; m >= 1; m >>= 1) sm += __shfl_xor(sm, m, 32);
  float w = ex / sm;
  if (half == 0) wts[(size_t)t * EE + e] = w;
  float wcur = w;
  for (int j = 0; j < KK; j++) {
    float v = wcur;
    int vi = e;
#pragma unroll
    for (int m = 16; m >= 1; m >>= 1) {
      float ov = __shfl_xor(v, m, 32);
      int oi = __shfl_xor(vi, m, 32);
      if (ov > v || (ov == v && oi < vi)) { v = ov; vi = oi; }
    }
    if (lane == 0) {
      int pos = atomicAdd(&cnt[vi], 1);
      tlist[(size_t)vi * BT + pos] = (t << 2) | j;
    }
    if (half == 0 && e == vi) wcur = -1.f;
  }
}

// ---------------------------------------------------------------------------
// Expert MLP via bf16 MFMA. 32 tokens/block, 4 waves, K-step 32.
// GEMM1 swapped: hidT[h][t] = W1T-image . xb^T  -> packed to hid LDS fraglets.
// GEMM2 natural: o[t][n] = hid . W2T-image      -> coalesced o_p stores.
// ---------------------------------------------------------------------------
__global__ __launch_bounds__(256, 2)
void k_mfma_expert(const u16* __restrict__ xb, const u32* __restrict__ img,
                   const float* __restrict__ b1, const float* __restrict__ b2,
                   const int* __restrict__ cnt, const int* __restrict__ tlist,
                   float* __restrict__ o_p) {
  __shared__ u32 stage[8192];          // 32 KB W-image K-step tile
  __shared__ u32 hid[ROWS * 256];      // 32 KB: 32 rows x 512 bf16 fraglets
  __shared__ int tk[ROWS], sl[ROWS];
  const int e = blockIdx.y;
  const int nt = cnt[e];
  const int start = blockIdx.x * ROWS;
  if (start >= nt) return;
  const int rows = min(ROWS, nt - start);
  const int tid = threadIdx.x;
  const int w = tid >> 6, lane = tid & 63;
  const int l15 = lane & 15, q = lane >> 4;
  if (tid < ROWS) {
    int i = min(tid, rows - 1);
    int ent = tlist[(size_t)e * BT + start + i];
    tk[tid] = ent >> 2;
    sl[tid] = ent & 3;
  }
  __syncthreads();
  const int tr0 = tk[l15], tr1 = tk[16 + l15];

  const u32* img1 = img + (size_t)e * 16 * 8192;         // W1T
  const u32* img2 = img + (size_t)(EE + e) * 16 * 8192;  // W2T

  f32x4 acc[8][2];
#pragma unroll
  for (int a = 0; a < 8; a++)
#pragma unroll
    for (int b = 0; b < 2; b++) acc[a][b] = {0.f, 0.f, 0.f, 0.f};

  // ---- GEMM1: hidT = W1T(512h x 512k) x X^T(512k x 32t) ----
  for (int s = 0; s < 16; s++) {
    __syncthreads();  // previous stage reads done
    const u32* src = img1 + s * 8192;
#pragma unroll
    for (int i = 0; i < 8; i++)
      gload_lds16(src + tid * 4 + i * 1024, stage + tid * 4 + i * 1024);
    short8 bf0 = *reinterpret_cast<const short8*>(xb + (size_t)tr0 * 512 + s * 32 + q * 8);
    short8 bf1 = *reinterpret_cast<const short8*>(xb + (size_t)tr1 * 512 + s * 32 + q * 8);
    __syncthreads();  // stage complete (barrier drains vmcnt)
#pragma unroll
    for (int hf = 0; hf < 8; hf++) {
      int h = w * 128 + hf * 16 + l15;
      short8 af = *reinterpret_cast<const short8*>(
          stage + h * 16 + ((q ^ ((h >> 2) & 3)) * 4));
      acc[hf][0] = __builtin_amdgcn_mfma_f32_16x16x32_bf16(af, bf0, acc[hf][0], 0, 0, 0);
      acc[hf][1] = __builtin_amdgcn_mfma_f32_16x16x32_bf16(af, bf1, acc[hf][1], 0, 0, 0);
    }
  }

  // bias + relu + pack hidT fragments into hid LDS (k-contiguous fraglets)
  {
    const float* b1e = b1 + (size_t)e * HH;
#pragma unroll
    for (int hf = 0; hf < 8; hf++) {
      int hbase = w * 128 + hf * 16 + q * 4;
      float4 bb = *reinterpret_cast<const float4*>(b1e + hbase);
      int f = hbase >> 3;               // = w*16 + hf*2 + (q>>1)
      int half8 = (q & 1) * 2;          // u32 offset within fraglet
#pragma unroll
      for (int tf = 0; tf < 2; tf++) {
        int t = tf * 16 + l15;
        float v0 = fmaxf(acc[hf][tf].x + bb.x, 0.f);
        float v1 = fmaxf(acc[hf][tf].y + bb.y, 0.f);
        float v2 = fmaxf(acc[hf][tf].z + bb.z, 0.f);
        float v3 = fmaxf(acc[hf][tf].w + bb.w, 0.f);
        u32x2 pk = { pack2bf(v0, v1), pack2bf(v2, v3) };
        *reinterpret_cast<u32x2*>(hid + t * 256 + ((f ^ (t & 7)) * 4) + half8) = pk;
      }
    }
  }

  f32x4 acc2[2][8];
#pragma unroll
  for (int a = 0; a < 2; a++)
#pragma unroll
    for (int b = 0; b < 8; b++) acc2[a][b] = {0.f, 0.f, 0.f, 0.f};

  // ---- GEMM2: o = hid(32t x 512h) x W2T-image(512h x 512n) ----
  for (int s = 0; s < 16; s++) {
    __syncthreads();  // hid writes done (s=0) / previous stage reads done
    const u32* src = img2 + s * 8192;
#pragma unroll
    for (int i = 0; i < 8; i++)
      gload_lds16(src + tid * 4 + i * 1024, stage + tid * 4 + i * 1024);
    __syncthreads();  // stage complete
    int fA = s * 4 + q;
    short8 a0 = *reinterpret_cast<const short8*>(
        hid + l15 * 256 + ((fA ^ (l15 & 7)) * 4));
    short8 a1 = *reinterpret_cast<const short8*>(
        hid + (16 + l15) * 256 + ((fA ^ (l15 & 7)) * 4));
#pragma unroll
    for (int nf = 0; nf < 8; nf++) {
      int n = w * 128 + nf * 16 + l15;
      short8 bfr = *reinterpret_cast<const short8*>(
          stage + n * 16 + ((q ^ ((n >> 2) & 3)) * 4));
      acc2[0][nf] = __builtin_amdgcn_mfma_f32_16x16x32_bf16(a0, bfr, acc2[0][nf], 0, 0, 0);
      acc2[1][nf] = __builtin_amdgcn_mfma_f32_16x16x32_bf16(a1, bfr, acc2[1][nf], 0, 0, 0);
    }
  }

  // epilogue: bias + store o (row-coalesced per 16-lane group)
  {
    const float* b2e = b2 + (size_t)e * DD;
#pragma unroll
    for (int nf = 0; nf < 8; nf++) {
      int n = w * 128 + nf * 16 + l15;
      float bb = b2e[n];
#pragma unroll
      for (int mf = 0; mf < 2; mf++) {
#pragma unroll
        for (int i = 0; i < 4; i++) {
          int r = mf * 16 + q * 4 + i;
          if (r < rows) {
            float val = acc2[mf][nf][i] + bb;
            o_p[((size_t)tk[r] * KK + sl[r]) * DD + n] = val;
          }
        }
      }
    }
  }
}

// ---------------------------------------------------------------------------
// Confidence nets (fp32 SIMT, reads o_p). grid (BT/16, E), 256 thr.
// ---------------------------------------------------------------------------
__global__ __launch_bounds__(256)
void k_conf(const float* __restrict__ o_p,
            const float* __restrict__ Wc1, const float* __restrict__ bc1,
            const float* __restrict__ Wc2, const float* __restrict__ bc2,
            const float* __restrict__ wts, const int* __restrict__ cnt,
            const int* __restrict__ tlist, float* __restrict__ cw) {
  __shared__ float os[16][DD];
  __shared__ float chb[16][CHN];
  __shared__ int tk[16], sl[16];
  const int e = blockIdx.y;
  const int nt = cnt[e];
  const int start = blockIdx.x * 16;
  if (start >= nt) return;
  const int rows = min(16, nt - start);
  const int tid = threadIdx.x;
  if (tid < 16) {
    int i = min(tid, rows - 1);
    int ent = tlist[(size_t)e * BT + start + i];
    tk[tid] = ent >> 2;
    sl[tid] = ent & 3;
  }
  __syncthreads();
  for (int idx = tid; idx < 16 * 128; idx += 256) {
    int m = idx >> 7, j = idx & 127;
    *reinterpret_cast<float4*>(&os[m][4 * j]) =
        *reinterpret_cast<const float4*>(
            &o_p[((size_t)tk[m] * KK + sl[m]) * DD + 4 * j]);
  }
  __syncthreads();
  const float* Wc1e = Wc1 + (size_t)e * DD * CHN;
#pragma unroll
  for (int r = 0; r < 2; r++) {
    int idx = tid + r * 256;
    int m = idx >> 5, c = idx & 31;
    float a = bc1[(size_t)e * CHN + c];
    for (int k = 0; k < DD; k++)
      a = fmaf(os[m][k], Wc1e[(size_t)k * CHN + c], a);
    chb[m][c] = fmaxf(a, 0.f);
  }
  __syncthreads();
  if (tid < 16) {
    int m = tid;
    float a = bc2[e];
#pragma unroll
    for (int c = 0; c < CHN; c++)
      a = fmaf(chb[m][c], Wc2[(size_t)e * CHN + c], a);
    float cv = 1.f / (1.f + expf(-a));
    if (m < rows)
      cw[(size_t)tk[m] * KK + sl[m]] = wts[(size_t)tk[m] * EE + e] * cv;
  }
}

// ---------------------------------------------------------------------------
// Combine: out[t] = sum_s cw*o / (sum_s cw + eps)
// ---------------------------------------------------------------------------
__global__ __launch_bounds__(256)
void k_combine(const float* __restrict__ o_p, const float* __restrict__ cw,
               float* __restrict__ out) {
  int gid = blockIdx.x * 256 + threadIdx.x;
  int t = gid >> 7;
  int j = gid & 127;
  float c0 = cw[t * 4 + 0], c1 = cw[t * 4 + 1];
  float c2 = cw[t * 4 + 2], c3 = cw[t * 4 + 3];
  float den = c0 + c1 + c2 + c3 + 1e-6f;
  const float4* base = reinterpret_cast<const float4*>(o_p) + (size_t)t * 4 * 128;
  float4 v0 = base[0 * 128 + j];
  float4 v1 = base[1 * 128 + j];
  float4 v2 = base[2 * 128 + j];
  float4 v3 = base[3 * 128 + j];
  float4 r;
  r.x = (c0 * v0.x + c1 * v1.x + c2 * v2.x + c3 * v3.x) / den;
  r.y = (c0 * v0.y + c1 * v1.y + c2 * v2.y + c3 * v3.y) / den;
  r.z = (c0 * v0.z + c1 * v1.z + c2 * v2.z + c3 * v3.z) / den;
  r.w = (c0 * v0.w + c1 * v1.w + c2 * v2.w + c3 * v3.w) / den;
  reinterpret_cast<float4*>(out)[gid] = r;
}

extern "C" void kernel_launch(void* const* d_in, const int* in_sizes, int n_in,
                              void* d_out, int out_size, void* d_ws, size_t ws_size,
                              hipStream_t stream) {
  const float* x   = (const float*)d_in[0];
  const float* W1  = (const float*)d_in[1];
  const float* b1  = (const float*)d_in[2];
  const float* W2  = (const float*)d_in[3];
  const float* b2  = (const float*)d_in[4];
  const float* Wg1 = (const float*)d_in[5];
  const float* bg1 = (const float*)d_in[6];
  const float* Wg2 = (const float*)d_in[7];
  const float* bg2 = (const float*)d_in[8];
  const float* Wc1 = (const float*)d_in[9];
  const float* bc1 = (const float*)d_in[10];
  const float* Wc2 = (const float*)d_in[11];
  const float* bc2 = (const float*)d_in[12];
  float* out = (float*)d_out;

  // workspace layout (~55 MB)
  u16* xb  = (u16*)d_ws;                                  // 2 MB
  u32* img = (u32*)(xb + (size_t)BT * DD);                // 32 MB (64 imgs x 16 steps x 32KB)
  float* h_g = (float*)(img + (size_t)64 * 16 * 8192);    // 4 MB
  float* wts = h_g + (size_t)BT * HH;                     // 256 KB
  float* cw  = wts + (size_t)BT * EE;                     // 32 KB
  float* o_p = cw + (size_t)BT * KK;                      // 16 MB
  int* cnt   = (int*)(o_p + (size_t)BT * KK * DD);        // 128 B
  int* tlist = cnt + EE;                                  // 256 KB

  hipMemsetAsync(cnt, 0, EE * sizeof(int), stream);
  k_cvt_x<<<(BT * DD) / (256 * 8), 256, 0, stream>>>(x, xb);
  k_tr_w<<<dim3(2, 16, 64), 256, 0, stream>>>(W1, W2, img);
  k_gate_hidden<<<dim3(BT / 16, 2), 256, 0, stream>>>(x, Wg1, bg1, h_g);
  k_gate_route<<<BT / 4, 256, 0, stream>>>(h_g, Wg2, bg2, wts, cnt, tlist);
  k_mfma_expert<<<dim3(BT / ROWS, EE), 256, 0, stream>>>(xb, img, b1, b2,
                                                         cnt, tlist, o_p);
  k_conf<<<dim3(BT / 16, EE), 256, 0, stream>>>(o_p, Wc1, bc1, Wc2, bc2,
                                                wts, cnt, tlist, cw);
  k_combine<<<(BT * (DD / 4)) / 256, 256, 0, stream>>>(o_p, cw, out);
}